// Round 8
// baseline (292.686 us; speedup 1.0000x reference)
//
#include <hip/hip_runtime.h>
#include <math.h>

#define B_G   256
#define IN_D  128
#define FD    256
#define HID   256
#define OUT_D 128
#define TXT   512
#define NTILES 511          // N = 65408 = 511 * 128 exactly
#define XKS   136           // LDS k-stride for staged Xbf tile (ushorts)

typedef short bf16x8 __attribute__((ext_vector_type(8)));
typedef float f32x4  __attribute__((ext_vector_type(4)));

__device__ __forceinline__ f32x4 MFMA(bf16x8 a, bf16x8 b, f32x4 c) {
    return __builtin_amdgcn_mfma_f32_16x16x32_bf16(a, b, c, 0, 0, 0);
}

// ---------------------------------------------------------------------------
// bf16 helpers (RNE)
// ---------------------------------------------------------------------------
__device__ __forceinline__ unsigned bf_rne(float x) {
    unsigned u = __float_as_uint(x);
    u += 0x7fffu + ((u >> 16) & 1u);
    return u >> 16;
}
__device__ __forceinline__ float bf_to_f(unsigned h) {
    return __uint_as_float(h << 16);
}
__device__ __forceinline__ bf16x8 pack_hi8(const float4& v0, const float4& v1) {
    uint4 h;
    h.x = bf_rne(v0.x) | (bf_rne(v0.y) << 16);
    h.y = bf_rne(v0.z) | (bf_rne(v0.w) << 16);
    h.z = bf_rne(v1.x) | (bf_rne(v1.y) << 16);
    h.w = bf_rne(v1.z) | (bf_rne(v1.w) << 16);
    return __builtin_bit_cast(bf16x8, h);
}
// 8 floats -> hi and lo fragments (3-term split precision)
__device__ __forceinline__ void split8hl(const float4& v0, const float4& v1,
                                         bf16x8& hf, bf16x8& lf) {
    float a[8] = {v0.x, v0.y, v0.z, v0.w, v1.x, v1.y, v1.z, v1.w};
    uint4 h, l;
    unsigned hh[8], ll[8];
#pragma unroll
    for (int i = 0; i < 8; i++) {
        hh[i] = bf_rne(a[i]);
        ll[i] = bf_rne(a[i] - bf_to_f(hh[i]));
    }
    h.x = hh[0] | (hh[1] << 16); h.y = hh[2] | (hh[3] << 16);
    h.z = hh[4] | (hh[5] << 16); h.w = hh[6] | (hh[7] << 16);
    l.x = ll[0] | (ll[1] << 16); l.y = ll[2] | (ll[3] << 16);
    l.z = ll[4] | (ll[5] << 16); l.w = ll[6] | (ll[7] << 16);
    hf = __builtin_bit_cast(bf16x8, h);
    lf = __builtin_bit_cast(bf16x8, l);
}

// ---------------------------------------------------------------------------
// K_wsplit (grid 36 x 256): parallel weight split, one block per (matrix, kc).
//  blocks 0..3  : W0 (K=128, N=256)
//  blocks 4..19 : Wq (K=512, N=256)
//  blocks 20..27: Wv (K=256, N=256)
//  blocks 28..35: Wo (K=256, N=256)
// ---------------------------------------------------------------------------
__global__ __launch_bounds__(256) void k_wsplit(
    const float* __restrict__ W0, const float* __restrict__ Wq,
    const float* __restrict__ Wv, const float* __restrict__ Wo,
    unsigned short* __restrict__ W0H, unsigned short* __restrict__ W0L,
    unsigned short* __restrict__ WqH, unsigned short* __restrict__ WqL,
    unsigned short* __restrict__ WvH, unsigned short* __restrict__ WvL,
    unsigned short* __restrict__ WoH, unsigned short* __restrict__ WoL)
{
    int blk = blockIdx.x, c = threadIdx.x;
    const float* W; unsigned short* H; unsigned short* L; int kc;
    if (blk < 4)       { W = W0; H = W0H; L = W0L; kc = blk; }
    else if (blk < 20) { W = Wq; H = WqH; L = WqL; kc = blk - 4; }
    else if (blk < 28) { W = Wv; H = WvH; L = WvL; kc = blk - 20; }
    else               { W = Wo; H = WoH; L = WoL; kc = blk - 28; }

    unsigned hw[16], lw[16];
#pragma unroll
    for (int kk = 0; kk < 32; kk++) {
        float v = W[(size_t)(kc * 32 + kk) * 256 + c];
        unsigned h = bf_rne(v);
        unsigned l = bf_rne(v - bf_to_f(h));
        if (kk & 1) { hw[kk >> 1] |= h << 16; lw[kk >> 1] |= l << 16; }
        else        { hw[kk >> 1] = h;        lw[kk >> 1] = l; }
    }
    size_t o = ((size_t)kc * 256 + c) * 32;
    uint4* hp = (uint4*)(H + o);
    uint4* lp = (uint4*)(L + o);
#pragma unroll
    for (int r = 0; r < 4; r++) {
        hp[r] = make_uint4(hw[r * 4], hw[r * 4 + 1], hw[r * 4 + 2], hw[r * 4 + 3]);
        lp[r] = make_uint4(lw[r * 4], lw[r * 4 + 1], lw[r * 4 + 2], lw[r * 4 + 3]);
    }
}

// ---------------------------------------------------------------------------
// K_prep (grid 512 x 256): Xbf convert + zero hsum/scores + offsets scan
// ---------------------------------------------------------------------------
__global__ __launch_bounds__(256) void k_prep(
    const float* __restrict__ X, const int* __restrict__ lens,
    unsigned short* __restrict__ Xbf, int* __restrict__ offsets,
    float* __restrict__ hsum, float* __restrict__ scores)
{
    int blk = blockIdx.x, tid = threadIdx.x;
    if (blk < NTILES) {
        size_t base = (size_t)blk * 16384;
#pragma unroll
        for (int it = 0; it < 8; it++) {
            size_t off = base + it * 2048 + tid * 8;
            const float4* p = (const float4*)(X + off);
            float4 v0 = p[0], v1 = p[1];
            *(uint4*)(Xbf + off) = __builtin_bit_cast(uint4, pack_hi8(v0, v1));
        }
        if (tid < 128) {
            hsum[blk * 128 + tid] = 0.f;
            scores[blk * 128 + tid] = 0.f;
        }
    } else {
        if (tid < 128) hsum[511 * 128 + tid] = 0.f;
        __shared__ int sc[B_G];
        sc[tid] = lens[tid];
        __syncthreads();
        for (int d = 1; d < 256; d <<= 1) {
            int v = (tid >= d) ? sc[tid - d] : 0;
            __syncthreads();
            sc[tid] += v;
            __syncthreads();
        }
        offsets[tid + 1] = sc[tid];
        if (tid == 0) offsets[0] = 0;
    }
}

// ---------------------------------------------------------------------------
// K_q (grid 16): q = TE @ WqS + bq
// ---------------------------------------------------------------------------
__global__ __launch_bounds__(256) void k_q(
    const float* __restrict__ TE,
    const unsigned short* __restrict__ WqH, const unsigned short* __restrict__ WqL,
    const float* __restrict__ bq, float* __restrict__ q)
{
    int blk = blockIdx.x;
    int rbase = (blk >> 2) * 64, cbase = (blk & 3) * 64;
    int tid = threadIdx.x, lane = tid & 63, w = tid >> 6;
    int ln = lane & 15, quad = lane >> 4;

    f32x4 acc[4] = {};
    int arow = rbase + w * 16 + ln;
#pragma unroll
    for (int kc = 0; kc < 16; kc++) {
        const float4* ap = (const float4*)(TE + (size_t)arow * TXT + kc * 32 + quad * 8);
        bf16x8 AH, AL;
        split8hl(ap[0], ap[1], AH, AL);
#pragma unroll
        for (int j = 0; j < 4; j++) {
            int c = cbase + 16 * j + ln;
            size_t bo = ((size_t)kc * 256 + c) * 32 + quad * 8;
            bf16x8 BH = *(const bf16x8*)(WqH + bo);
            bf16x8 BL = *(const bf16x8*)(WqL + bo);
            acc[j] = MFMA(AH, BH, acc[j]);
            acc[j] = MFMA(AH, BL, acc[j]);
            acc[j] = MFMA(AL, BH, acc[j]);
        }
    }
#pragma unroll
    for (int j = 0; j < 4; j++) {
        int c = cbase + 16 * j + ln;
        float bb = bq[c];
#pragma unroll
        for (int r = 0; r < 4; r++) {
            int row = rbase + w * 16 + quad * 4 + r;
            q[(size_t)row * FD + c] = acc[j][r] + bb;
        }
    }
}

// ---------------------------------------------------------------------------
// K_qk (grid 16): qk[b,f] = sum_c q[b,c] * Wk[f,c]
// ---------------------------------------------------------------------------
__global__ __launch_bounds__(256) void k_qk(
    const float* __restrict__ q, const float* __restrict__ Wk,
    float* __restrict__ qk)
{
    int blk = blockIdx.x;
    int rbase = (blk >> 2) * 64, cbase = (blk & 3) * 64;
    int tid = threadIdx.x, lane = tid & 63, w = tid >> 6;
    int ln = lane & 15, quad = lane >> 4;

    f32x4 acc[4] = {};
    int arow = rbase + w * 16 + ln;
#pragma unroll
    for (int kc = 0; kc < 8; kc++) {
        const float4* ap = (const float4*)(q + (size_t)arow * FD + kc * 32 + quad * 8);
        bf16x8 AH, AL;
        split8hl(ap[0], ap[1], AH, AL);
#pragma unroll
        for (int j = 0; j < 4; j++) {
            int f = cbase + 16 * j + ln;
            const float4* bp = (const float4*)(Wk + (size_t)f * FD + kc * 32 + quad * 8);
            bf16x8 BH, BL;
            split8hl(bp[0], bp[1], BH, BL);
            acc[j] = MFMA(AH, BH, acc[j]);
            acc[j] = MFMA(AH, BL, acc[j]);
            acc[j] = MFMA(AL, BH, acc[j]);
        }
    }
#pragma unroll
    for (int j = 0; j < 4; j++) {
        int f = cbase + 16 * j + ln;
#pragma unroll
        for (int r = 0; r < 4; r++) {
            int row = rbase + w * 16 + quad * 4 + r;
            qk[(size_t)row * FD + f] = acc[j][r];
        }
    }
}

// ---------------------------------------------------------------------------
// K_l0 (grid 2 x 511): h = relu(Xbf @ W0 + b0) over packed 128-node tiles.
// ---------------------------------------------------------------------------
__global__ __launch_bounds__(256) void k_l0(
    const unsigned short* __restrict__ Xbf,
    const unsigned short* __restrict__ W0H, const unsigned short* __restrict__ W0L,
    const float* __restrict__ b0, const float* __restrict__ qk,
    const int* __restrict__ offsets,
    float* __restrict__ scores, float* __restrict__ hsum)
{
    int t = blockIdx.y, bx = blockIdx.x;
    int n0 = t * 128;
    int tid = threadIdx.x, lane = tid & 63, w = tid >> 6;
    int ln = lane & 15, quad = lane >> 4;
    int i2 = w & 1, j2 = w >> 1;

    __shared__ __align__(16) unsigned short Xs[128 * XKS];
    __shared__ int offs[257];
    __shared__ float qks[2][128];
    __shared__ float bsh[128];

    offs[tid] = offsets[tid];
    if (tid == 0) offs[256] = offsets[256];
    __syncthreads();

    int lo = 0, hi = 255;
#pragma unroll
    for (int s = 0; s < 8; s++) {
        int mid = (lo + hi + 1) >> 1;
        if (offs[mid] <= n0) lo = mid; else hi = mid - 1;
    }
    int g0 = lo;
    lo = g0; hi = 255;
#pragma unroll
    for (int s = 0; s < 8; s++) {
        int mid = (lo + hi + 1) >> 1;
        if (offs[mid] <= n0 + 127) lo = mid; else hi = mid - 1;
    }
    int g1 = lo;
    int boundary = (g1 > g0) ? offs[g1] : 0x7fffffff;

    if (tid < 128) {
        bsh[tid] = b0[bx * 128 + tid];
        qks[0][tid] = qk[(size_t)g0 * FD + bx * 128 + tid];
        qks[1][tid] = qk[(size_t)g1 * FD + bx * 128 + tid];
    }
#pragma unroll
    for (int it = 0; it < 8; it++) {
        int row = it * 16 + (tid >> 4);
        int kq = (tid & 15) * 8;
        *(uint4*)(Xs + row * XKS + kq) =
            *(const uint4*)(Xbf + (size_t)(n0 + row) * IN_D + kq);
    }
    __syncthreads();

    f32x4 acc[4][4] = {};
#pragma unroll
    for (int kc = 0; kc < 4; kc++) {
        bf16x8 AH[4], BH[4], BL[4];
#pragma unroll
        for (int i = 0; i < 4; i++)
            AH[i] = *(const bf16x8*)(Xs + (i2 * 64 + 16 * i + ln) * XKS + kc * 32 + quad * 8);
#pragma unroll
        for (int j = 0; j < 4; j++) {
            int c = bx * 128 + j2 * 64 + 16 * j + ln;
            size_t bo = ((size_t)kc * 256 + c) * 32 + quad * 8;
            BH[j] = *(const bf16x8*)(W0H + bo);
            BL[j] = *(const bf16x8*)(W0L + bo);
        }
#pragma unroll
        for (int i = 0; i < 4; i++)
#pragma unroll
            for (int j = 0; j < 4; j++) {
                acc[i][j] = MFMA(AH[i], BH[j], acc[i][j]);
                acc[i][j] = MFMA(AH[i], BL[j], acc[i][j]);
            }
    }

    float sp[4][4];
    float cs[4][2];
#pragma unroll
    for (int i = 0; i < 4; i++)
#pragma unroll
        for (int r = 0; r < 4; r++) sp[i][r] = 0.f;
#pragma unroll
    for (int j = 0; j < 4; j++) { cs[j][0] = 0.f; cs[j][1] = 0.f; }

#pragma unroll
    for (int i = 0; i < 4; i++)
#pragma unroll
        for (int j = 0; j < 4; j++) {
            int cl = j2 * 64 + 16 * j + ln;
            float bb = bsh[cl];
#pragma unroll
            for (int r = 0; r < 4; r++) {
                int node = i2 * 64 + 16 * i + quad * 4 + r;
                int gb = (n0 + node >= boundary) ? 1 : 0;
                float h = fmaxf(acc[i][j][r] + bb, 0.f);
                sp[i][r] = fmaf(h, qks[gb][cl], sp[i][r]);
                cs[j][gb] += h;
            }
        }
#pragma unroll
    for (int i = 0; i < 4; i++)
#pragma unroll
        for (int r = 0; r < 4; r++) {
            float s = sp[i][r];
            s += __shfl_xor(s, 1); s += __shfl_xor(s, 2);
            s += __shfl_xor(s, 4); s += __shfl_xor(s, 8);
            if (ln == 0) {
                int node = i2 * 64 + 16 * i + quad * 4 + r;
                atomicAdd(&scores[n0 + node], s);
            }
        }
#pragma unroll
    for (int j = 0; j < 4; j++) {
        int cl = j2 * 64 + 16 * j + ln;
#pragma unroll
        for (int gb = 0; gb < 2; gb++) {
            float s = cs[j][gb];
            s += __shfl_xor(s, 16); s += __shfl_xor(s, 32);
            if (quad == 0 && (gb == 0 || g1 > g0)) {
                int g = gb ? g1 : g0;
                atomicAdd(&hsum[(size_t)g * FD + bx * 128 + cl], s);
            }
        }
    }
}

// ---------------------------------------------------------------------------
// K_mid (grid 260):
//  blocks 0..3  : vsum = hsum@WvS + len*bv ; wvec = vsum@WoS
//  blocks 4..259: per-graph softmax stats
// ---------------------------------------------------------------------------
__global__ __launch_bounds__(256) void k_mid(
    const float* __restrict__ scores, const float* __restrict__ hsum,
    const unsigned short* __restrict__ WvH, const unsigned short* __restrict__ WvL,
    const float* __restrict__ bv,
    const unsigned short* __restrict__ WoH, const unsigned short* __restrict__ WoL,
    const int* __restrict__ offsets,
    float* __restrict__ wvec, float* __restrict__ smax, float* __restrict__ dinv)
{
    int blk = blockIdx.x, tid = threadIdx.x;
    if (blk < 4) {
        __shared__ float vs[64 * 260];
        __shared__ int offs2[65];
        int base = blk * 64;
        int lane = tid & 63, w = tid >> 6;
        int ln = lane & 15, quad = lane >> 4;
        if (tid < 65) offs2[tid] = offsets[base + tid];
        __syncthreads();

        f32x4 acc[4][4] = {};
#pragma unroll
        for (int kc = 0; kc < 8; kc++) {
            bf16x8 AH[4], AL[4], BH[4], BL[4];
#pragma unroll
            for (int i = 0; i < 4; i++) {
                const float4* ap = (const float4*)(hsum + (size_t)(base + 16 * i + ln) * FD + kc * 32 + quad * 8);
                split8hl(ap[0], ap[1], AH[i], AL[i]);
            }
#pragma unroll
            for (int j = 0; j < 4; j++) {
                int c = w * 64 + 16 * j + ln;
                size_t bo = ((size_t)kc * 256 + c) * 32 + quad * 8;
                BH[j] = *(const bf16x8*)(WvH + bo);
                BL[j] = *(const bf16x8*)(WvL + bo);
            }
#pragma unroll
            for (int i = 0; i < 4; i++)
#pragma unroll
                for (int j = 0; j < 4; j++) {
                    acc[i][j] = MFMA(AH[i], BH[j], acc[i][j]);
                    acc[i][j] = MFMA(AH[i], BL[j], acc[i][j]);
                    acc[i][j] = MFMA(AL[i], BH[j], acc[i][j]);
                }
        }
#pragma unroll
        for (int i = 0; i < 4; i++)
#pragma unroll
            for (int j = 0; j < 4; j++) {
                int c = w * 64 + 16 * j + ln;
                float bvc = bv[c];
#pragma unroll
                for (int r = 0; r < 4; r++) {
                    int row = 16 * i + quad * 4 + r;
                    float len = (float)(offs2[row + 1] - offs2[row]);
                    vs[row * 260 + c] = acc[i][j][r] + len * bvc;
                }
            }
        __syncthreads();

        f32x4 acc2[4][4] = {};
#pragma unroll
        for (int kc = 0; kc < 8; kc++) {
            bf16x8 AH[4], AL[4], BH[4], BL[4];
#pragma unroll
            for (int i = 0; i < 4; i++) {
                const float4* ap = (const float4*)(vs + (16 * i + ln) * 260 + kc * 32 + quad * 8);
                split8hl(ap[0], ap[1], AH[i], AL[i]);
            }
#pragma unroll
            for (int j = 0; j < 4; j++) {
                int c = w * 64 + 16 * j + ln;
                size_t bo = ((size_t)kc * 256 + c) * 32 + quad * 8;
                BH[j] = *(const bf16x8*)(WoH + bo);
                BL[j] = *(const bf16x8*)(WoL + bo);
            }
#pragma unroll
            for (int i = 0; i < 4; i++)
#pragma unroll
                for (int j = 0; j < 4; j++) {
                    acc2[i][j] = MFMA(AH[i], BH[j], acc2[i][j]);
                    acc2[i][j] = MFMA(AH[i], BL[j], acc2[i][j]);
                    acc2[i][j] = MFMA(AL[i], BH[j], acc2[i][j]);
                }
        }
#pragma unroll
        for (int i = 0; i < 4; i++)
#pragma unroll
            for (int j = 0; j < 4; j++) {
                int c = w * 64 + 16 * j + ln;
#pragma unroll
                for (int r = 0; r < 4; r++) {
                    int row = 16 * i + quad * 4 + r;
                    wvec[(size_t)(base + row) * HID + c] = acc2[i][j][r];
                }
            }
    } else {
        int b = blk - 4;
        int off = offsets[b], len = offsets[b + 1] - off;
        __shared__ float redm[4], reds[4];
        float m = -INFINITY;
        for (int i = tid; i < len; i += 256) m = fmaxf(m, scores[off + i]);
        for (int d = 1; d < 64; d <<= 1) m = fmaxf(m, __shfl_xor(m, d));
        if ((tid & 63) == 0) redm[tid >> 6] = m;
        __syncthreads();
        m = fmaxf(fmaxf(redm[0], redm[1]), fmaxf(redm[2], redm[3]));
        float s = 0.f;
        for (int i = tid; i < len; i += 256) s += expf(scores[off + i] - m);
        for (int d = 1; d < 64; d <<= 1) s += __shfl_xor(s, d);
        if ((tid & 63) == 0) reds[tid >> 6] = s;
        __syncthreads();
        if (tid == 0) {
            smax[b] = m;
            dinv[b] = 1.0f / (reds[0] + reds[1] + reds[2] + reds[3]);
        }
    }
}

// ---------------------------------------------------------------------------
// K_tab (grid 256): per-graph piecewise-linear table for
//   f(p) = sum_k relu(p*w_k + bo_k) * W2[k,:] + b2  =  p*A_j + B_j on segment j.
// Events at t_k = -bo_k/w_k in (0,1); bitonic sort; sweep writes
// T[b][j][c] = (A_j[c], B_j[c]) float2, rows 0..nevents; tsort[b][k] thresholds.
// EXACT fp32 (no bf16 anywhere).
// ---------------------------------------------------------------------------
__global__ __launch_bounds__(256) void k_tab(
    const float* __restrict__ wvec, const float* __restrict__ bo,
    const float* __restrict__ W2, const float* __restrict__ b2,
    float2* __restrict__ Ttab, float* __restrict__ tsort)
{
    int b = blockIdx.x, tid = threadIdx.x;
    __shared__ float wsh[256], bosh[256];
    __shared__ unsigned long long key[256];
    __shared__ unsigned char act[256];
    __shared__ float partA[2][128], partB[2][128];

    float w = wvec[(size_t)b * HID + tid];
    float bv = bo[tid];
    wsh[tid] = w; bosh[tid] = bv;

    // classify: cls 0=never 1=always 2=event+ 3=event-
    int cls;
    float t = 0.f;
    if (w > 0.f)      { t = -bv / w; cls = (t <= 0.f) ? 1 : (t >= 1.f ? 0 : 2); }
    else if (w < 0.f) { t = -bv / w; cls = (t <= 0.f) ? 0 : (t >= 1.f ? 1 : 3); }
    else              { cls = (bv > 0.f) ? 1 : 0; }
    unsigned kb = (cls >= 2) ? __float_as_uint(t) : 0x7f800000u;
    key[tid] = ((unsigned long long)kb << 32) | ((unsigned)cls << 16) | (unsigned)tid;
    act[tid] = (cls == 1 || cls == 3) ? 1 : 0;   // active at p=0+
    __syncthreads();

    // bitonic sort ascending (events in (0,1) first, INF tail)
    for (int k2 = 2; k2 <= 256; k2 <<= 1) {
        for (int jj = k2 >> 1; jj > 0; jj >>= 1) {
            __syncthreads();
            int ixj = tid ^ jj;
            if (ixj > tid) {
                bool up = ((tid & k2) == 0);
                unsigned long long a = key[tid], c2 = key[ixj];
                if (up ? (a > c2) : (a < c2)) { key[tid] = c2; key[ixj] = a; }
            }
        }
    }
    __syncthreads();
    tsort[(size_t)b * 256 + tid] = __uint_as_float((unsigned)(key[tid] >> 32));

    // base sums over active set, split k-range across 2 groups
    int g = tid >> 7, c = tid & 127;
    float A = 0.f, Bv = (g == 0) ? b2[c] : 0.f;
    for (int kk = 128 * g; kk < 128 * g + 128; kk++) {
        float m = act[kk] ? 1.f : 0.f;
        float wc = W2[(size_t)kk * OUT_D + c] * m;
        A = fmaf(wsh[kk], wc, A);
        Bv = fmaf(bosh[kk], wc, Bv);
    }
    partA[g][c] = A; partB[g][c] = Bv;
    __syncthreads();

    // sweep (threads 0..127, one output column each)
    if (tid < 128) {
        float Aa = partA[0][tid] + partA[1][tid];
        float Bb = partB[0][tid] + partB[1][tid];
        size_t rb = (size_t)b * 257 * 128;
        Ttab[rb + tid] = make_float2(Aa, Bb);
        for (int j = 1; j <= 256; j++) {
            unsigned long long kk = key[j - 1];
            if ((unsigned)(kk >> 32) >= 0x7f800000u) break;   // uniform
            float s = (((kk >> 16) & 0xffffu) == 2u) ? 1.f : -1.f;
            int id = (int)(kk & 0xffffu);
            float wc = W2[(size_t)id * OUT_D + tid] * s;
            Aa = fmaf(wsh[id], wc, Aa);
            Bb = fmaf(bosh[id], wc, Bb);
            Ttab[rb + (size_t)j * 128 + tid] = make_float2(Aa, Bb);
        }
    }
}

// ---------------------------------------------------------------------------
// K_out (grid 511 x 256): y_n = p_n * A_j + B_j  (exact table lookup).
// Thread t: node = t>>1, col-half = t&1 (64 cols).
// ---------------------------------------------------------------------------
__global__ __launch_bounds__(256) void k_out(
    const float* __restrict__ scores, const float* __restrict__ tsort,
    const float2* __restrict__ Ttab, const float* __restrict__ smax,
    const float* __restrict__ dinv, const int* __restrict__ offsets,
    float* __restrict__ Y)
{
    int tt = blockIdx.x;
    int n0 = tt * 128;
    int tid = threadIdx.x;

    __shared__ int offs[257];
    __shared__ float ts[2][256];
    __shared__ float sd[4];

    offs[tid] = offsets[tid];
    if (tid == 0) offs[256] = offsets[256];
    __syncthreads();

    int lo = 0, hi = 255;
#pragma unroll
    for (int s = 0; s < 8; s++) {
        int mid = (lo + hi + 1) >> 1;
        if (offs[mid] <= n0) lo = mid; else hi = mid - 1;
    }
    int g0 = lo;
    lo = g0; hi = 255;
#pragma unroll
    for (int s = 0; s < 8; s++) {
        int mid = (lo + hi + 1) >> 1;
        if (offs[mid] <= n0 + 127) lo = mid; else hi = mid - 1;
    }
    int g1 = lo;
    int boundary = (g1 > g0) ? offs[g1] : 0x7fffffff;

    ts[0][tid] = tsort[(size_t)g0 * 256 + tid];
    ts[1][tid] = tsort[(size_t)g1 * 256 + tid];
    if (tid == 0) { sd[0] = smax[g0]; sd[1] = dinv[g0]; sd[2] = smax[g1]; sd[3] = dinv[g1]; }
    __syncthreads();

    int half = tid & 1, nl = tid >> 1;
    int node = n0 + nl;
    int gb = (node >= boundary) ? 1 : 0;
    float p = expf(scores[node] - sd[gb * 2]) * sd[gb * 2 + 1];

    // j = # thresholds <= p
    int j = 0;
#pragma unroll
    for (int step = 128; step >= 1; step >>= 1) {
        int cand = j + step;
        if (cand <= 256 && ts[gb][cand - 1] <= p) j = cand;
    }

    const float4* row = (const float4*)(Ttab + ((size_t)(gb ? g1 : g0) * 257 + j) * 128 + half * 64);
    float4* yrow = (float4*)(Y + (size_t)node * OUT_D + half * 64);
#pragma unroll
    for (int u = 0; u < 16; u++) {
        float4 a = row[2 * u];
        float4 bq4 = row[2 * u + 1];
        float4 y;
        y.x = fmaf(p, a.x, a.y);
        y.y = fmaf(p, a.z, a.w);
        y.z = fmaf(p, bq4.x, bq4.y);
        y.w = fmaf(p, bq4.z, bq4.w);
        yrow[u] = y;
    }
}

// ---------------------------------------------------------------------------
extern "C" void kernel_launch(void* const* d_in, const int* in_sizes, int n_in,
                              void* d_out, int out_size, void* d_ws, size_t ws_size,
                              hipStream_t stream)
{
    const float* X        = (const float*)d_in[0];
    const float* text_emb = (const float*)d_in[1];
    const int*   lens     = (const int*)d_in[2];
    const float* W0       = (const float*)d_in[3];
    const float* b0       = (const float*)d_in[4];
    const float* Wq       = (const float*)d_in[5];
    const float* bq       = (const float*)d_in[6];
    const float* Wk       = (const float*)d_in[7];
    // d_in[8] = bk : softmax-invariant, unused
    const float* Wv       = (const float*)d_in[9];
    const float* bv       = (const float*)d_in[10];
    const float* Wo       = (const float*)d_in[11];
    const float* bo       = (const float*)d_in[12];
    const float* W2       = (const float*)d_in[13];
    const float* b2       = (const float*)d_in[14];
    float* Y = (float*)d_out;

    char* base = (char*)d_ws;
    size_t o = 0;
    int*   offsets = (int*)(base + o);                  o += 4096;
    float* qbuf    = (float*)(base + o);                o += 262144;
    float* qkbuf   = (float*)(base + o);                o += 262144;
    float* wvec    = (float*)(base + o);                o += 262144;
    float* smaxb   = (float*)(base + o);                o += 1024;
    float* dinvb   = (float*)(base + o);                o += 1024;
    float* hsum    = (float*)(base + o);                o += 262144;
    float* scores  = (float*)(base + o);                o += 262144;
    unsigned short* WqH = (unsigned short*)(base + o);  o += 262144;
    unsigned short* WqL = (unsigned short*)(base + o);  o += 262144;
    unsigned short* WvH = (unsigned short*)(base + o);  o += 131072;
    unsigned short* WvL = (unsigned short*)(base + o);  o += 131072;
    unsigned short* WoH = (unsigned short*)(base + o);  o += 131072;
    unsigned short* WoL = (unsigned short*)(base + o);  o += 131072;
    unsigned short* W0H = (unsigned short*)(base + o);  o += 65536;
    unsigned short* W0L = (unsigned short*)(base + o);  o += 65536;
    unsigned short* Xbf = (unsigned short*)(base + o);  o += 16744448;
    float* tsortb  = (float*)(base + o);                o += 262144;
    float2* Ttab   = (float2*)(base + o);               o += (size_t)256 * 257 * 128 * 8;

    k_wsplit<<<36, 256, 0, stream>>>(W0, Wq, Wv, Wo,
                                     W0H, W0L, WqH, WqL, WvH, WvL, WoH, WoL);
    k_prep<<<512, 256, 0, stream>>>(X, lens, Xbf, offsets, hsum, scores);
    k_q<<<16, 256, 0, stream>>>(text_emb, WqH, WqL, bq, qbuf);
    k_qk<<<16, 256, 0, stream>>>(qbuf, Wk, qkbuf);
    k_l0<<<dim3(2, NTILES), 256, 0, stream>>>(Xbf, W0H, W0L, b0, qkbuf, offsets, scores, hsum);
    k_mid<<<260, 256, 0, stream>>>(scores, hsum, WvH, WvL, bv, WoH, WoL, offsets,
                                   wvec, smaxb, dinvb);
    k_tab<<<256, 256, 0, stream>>>(wvec, bo, W2, b2, Ttab, tsortb);
    k_out<<<NTILES, 256, 0, stream>>>(scores, tsortb, Ttab, smaxb, dinvb, offsets, Y);
}